// Round 7
// baseline (31.267 us; speedup 1.0000x reference)
//
#include <hip/hip_runtime.h>

// ToChoices: out[b,h,w,s,c] = (shuffle_indices[b,s] ? reals : fakes)[b,h,w,c]
// reals/fakes (64,256,256,3) f32, shuffle_indices (64,2) int, out (64,256,256,2,3) f32.
//
// Structure (R5, 30.8us): LDS-stage a pixel tile per block so EVERY global
// load and store is lane-contiguous (lane i <-> base + i*16B). The
// 12B-granularity interleave permutation happens via LDS scalar reads.
// Cached stores (R3: nt+strided = 4x regression; R6: nt+contiguous = neutral).
//
// R7 change: TILE_PIX 1024 -> 2048 (48KB LDS, 2048 blocks). Halves block
// count & barrier events, doubles per-thread MLP (6 staged loads / 12 stores
// in flight). Fill kernels hit 7TB/s at 9% occupancy -> 3 blocks/CU is ample.

typedef float f32x4 __attribute__((ext_vector_type(4)));

#define HW 65536                      // pixels per image
#define TILE_PIX 2048                 // pixels per block-tile
#define TILES_PER_B (HW / TILE_PIX)   // 32
#define SRC_FLOATS (TILE_PIX * 3)     // 6144 floats staged per source (24 KB)
#define OUT_FLOATS (TILE_PIX * 6)     // 12288 floats out per tile (48 KB)
#define NLOAD (SRC_FLOATS / 4 / 256)  // 6 float4 loads per thread per source
#define NSTORE (OUT_FLOATS / 4 / 256) // 12 float4 stores per thread

__global__ __launch_bounds__(256) void tochoices_kernel(
    const float* __restrict__ reals,
    const float* __restrict__ fakes,
    const int* __restrict__ idx,
    float* __restrict__ out)
{
    __shared__ __align__(16) float lds[SRC_FLOATS + 4 + SRC_FLOATS];
    float* ldsA = lds;
    float* ldsB = lds + SRC_FLOATS + 4;

    int blk  = blockIdx.x;
    int b    = blk / TILES_PER_B;
    int tile = blk - b * TILES_PER_B;
    int t    = threadIdx.x;

    int i0 = idx[b * 2 + 0];          // slot 0: 0 = fakes, 1 = reals
    int i1 = idx[b * 2 + 1];

    int inbase = b * (HW * 3) + tile * SRC_FLOATS;   // < 12.6M, fits int

    // ---- Phase 1: contiguous global -> LDS staging ------------------------
    const f32x4* pA = (const f32x4*)((i0 ? reals : fakes) + inbase);
    #pragma unroll
    for (int k = 0; k < NLOAD; ++k)
        ((f32x4*)ldsA)[t + 256 * k] = pA[t + 256 * k];

    const float* B = ldsA;            // if both slots same image, reuse A
    if (i1 != i0) {                   // block-uniform branch
        const f32x4* pB = (const f32x4*)((i1 ? reals : fakes) + inbase);
        #pragma unroll
        for (int k = 0; k < NLOAD; ++k)
            ((f32x4*)ldsB)[t + 256 * k] = pB[t + 256 * k];
        B = ldsB;
    }
    __syncthreads();

    // ---- Phase 2: permuted LDS reads -> contiguous cached stores ----------
    // Tile-local out float4 index g; pixel-pair h = g/3, r = g%3; components
    // (A = slot-0 source, B = slot-1 source, base 6h):
    //   r=0: A+0 A+1 A+2 B+0
    //   r=1: B+1 B+2 A+3 A+4
    //   r=2: A+5 B+3 B+4 B+5
    f32x4* o = (f32x4*)(out + (long)b * (HW * 6) + tile * OUT_FLOATS);
    #pragma unroll
    for (int k = 0; k < NSTORE; ++k) {
        int g = t + 256 * k;
        int h = g / 3;
        int r = g - 3 * h;            // g % 3
        const float* a6 = ldsA + 6 * h;
        const float* b6 = B    + 6 * h;

        const float* px = (r == 0) ? a6 + 0 : (r == 1) ? b6 + 1 : a6 + 5;
        const float* py = (r == 0) ? a6 + 1 : (r == 1) ? b6 + 2 : b6 + 3;
        const float* pz = (r == 0) ? a6 + 2 : (r == 1) ? a6 + 3 : b6 + 4;
        const float* pw = (r == 0) ? b6 + 0 : (r == 1) ? a6 + 4 : b6 + 5;

        f32x4 v;
        v.x = *px; v.y = *py; v.z = *pz; v.w = *pw;
        o[g] = v;                     // lane-contiguous 16B store
    }
}

extern "C" void kernel_launch(void* const* d_in, const int* in_sizes, int n_in,
                              void* d_out, int out_size, void* d_ws, size_t ws_size,
                              hipStream_t stream) {
    const float* reals = (const float*)d_in[0];
    const float* fakes = (const float*)d_in[1];
    const int*   idx   = (const int*)d_in[2];
    float* out = (float*)d_out;

    const int grid = 64 * TILES_PER_B;    // 2048 blocks, one 2048-pixel tile each
    tochoices_kernel<<<grid, 256, 0, stream>>>(reals, fakes, idx, out);
}

// Round 8
// 31.186 us; speedup vs baseline: 1.0026x; 1.0026x over previous
//
#include <hip/hip_runtime.h>

// ToChoices: out[b,h,w,s,c] = (shuffle_indices[b,s] ? reals : fakes)[b,h,w,c]
// reals/fakes (64,256,256,3) f32, shuffle_indices (64,2) int, out (64,256,256,2,3) f32.
//
// R8: LDS-free, fully-contiguous mapping. Flatten output to (pixel,slot)
// items of 12B. Item i = (b*HW + pix)*2 + slot writes out[i*3 .. i*3+2]:
// lane i of a wave -> 12 contiguous bytes -> each wave store op is a 768B
// contiguous line-aligned burst (64*12B). Reads: lane i pulls 12B from
// source idx[b, i&1] at pixel i>>1; even/odd lanes each sweep a contiguous
// fully-consumed 384B (6-line) range, coinciding when both slots pick the
// same image (L2 dedup). No LDS round-trip, no barrier (R5-R7 plateau at
// ~31us suggests that was the residual vs the 6.3TB/s copy ceiling).
// Cached stores (R3: nt = regression; R6: nt = neutral).

#define HW 65536
#define ITEMS (64 * HW * 2)        // 8,388,608 (pixel,slot) items
#define ITEMS_PER_T 4
#define TOTAL_T (ITEMS / ITEMS_PER_T)   // 2,097,152 threads

__global__ __launch_bounds__(256) void tochoices_kernel(
    const float* __restrict__ reals,
    const float* __restrict__ fakes,
    const int* __restrict__ idx,
    float* __restrict__ out)
{
    int t0 = blockIdx.x * blockDim.x + threadIdx.x;

    #pragma unroll
    for (int k = 0; k < ITEMS_PER_T; ++k) {
        int i    = t0 + k * TOTAL_T;       // item index, wave-contiguous
        int b    = i >> 17;                // / (HW*2)
        int slot = i & 1;
        int pix  = (i >> 1) & (HW - 1);

        const float* s = idx[b * 2 + slot] ? reals : fakes;
        const float* p = s + (b * HW + pix) * 3;    // < 12.6M floats, fits int
        float x = p[0], y = p[1], z = p[2];         // -> global_load_dwordx3

        float* o = out + (long)i * 3;
        o[0] = x; o[1] = y; o[2] = z;               // -> global_store_dwordx3
    }
}

extern "C" void kernel_launch(void* const* d_in, const int* in_sizes, int n_in,
                              void* d_out, int out_size, void* d_ws, size_t ws_size,
                              hipStream_t stream) {
    const float* reals = (const float*)d_in[0];
    const float* fakes = (const float*)d_in[1];
    const int*   idx   = (const int*)d_in[2];
    float* out = (float*)d_out;

    const int block = 256;
    const int grid = TOTAL_T / block;      // 8192
    tochoices_kernel<<<grid, block, 0, stream>>>(reals, fakes, idx, out);
}